// Round 1
// baseline (5156.446 us; speedup 1.0000x reference)
//
#include <hip/hip_runtime.h>
#include <cstdint>
#include <cstddef>

typedef unsigned int u32;
typedef unsigned long long u64;

#define NB 8
#define GH 128
#define GW 128
#define NA 9
#define NC 86
#define NANCH (GH*GW*NA)      /* 147456 */
#define TOPK 1000
#define KCAP 1024
#define CANDCAP 4096
#define VALIDCAP 65536
#define NBINS 65536

/* ---- workspace layout (bytes) ---- */
#define OFF_HIST      ((size_t)0)
#define SZ_HIST       ((size_t)NB*NBINS*4)            /* 2,097,152 */
#define OFF_VCNT      (OFF_HIST + SZ_HIST)
#define OFF_CCNT      (OFF_VCNT + 32)
#define MEMSET_BYTES  (OFF_CCNT + 32)                 /* zero hist + counters */
#define OFF_CUT       (MEMSET_BYTES)
#define OFF_M         (OFF_CUT + 32)
#define OFF_KEEP      (OFF_M + 32)                    /* NB*16*8 = 1024 */
#define OFF_VBUF      (OFF_KEEP + 1024)
#define SZ_VBUF       ((size_t)NB*VALIDCAP*8)
#define OFF_CBUF      (OFF_VBUF + SZ_VBUF)
#define SZ_CBUF       ((size_t)NB*CANDCAP*8)
#define OFF_DET       (OFF_CBUF + SZ_CBUF)
#define SZ_DET        ((size_t)NB*KCAP*8*4)
#define OFF_COR       (OFF_DET + SZ_DET)
#define SZ_COR        ((size_t)NB*KCAP*16)
#define OFF_AREA      (OFF_COR + SZ_COR)
#define SZ_AREA       ((size_t)NB*KCAP*4)
#define OFF_MASK      (OFF_AREA + SZ_AREA)
#define SZ_MASK       ((size_t)NB*KCAP*16*8)

__device__ __forceinline__ u64 shfl64(u64 v, int src) {
    int lo = __shfl((int)(v & 0xffffffffull), src, 64);
    int hi = __shfl((int)(v >> 32), src, 64);
    return ((u64)(u32)hi << 32) | (u32)lo;
}

/* 1: strided score scan -> histogram + valid (key,~idx) compaction */
__global__ void k1_hist(const float* __restrict__ in, u32* __restrict__ hist,
                        int* __restrict__ vcnt, u64* __restrict__ vbuf) {
    int gid = blockIdx.x * blockDim.x + threadIdx.x;
    if (gid >= NB * NANCH) return;
    float sc = in[(size_t)gid * NC + 5];
    if (sc >= 0.5f) {
        int b = gid / NANCH;
        u32 n = (u32)(gid - b * NANCH);
        u32 key = __float_as_uint(sc) ^ 0x80000000u;   /* positive floats: monotone */
        atomicAdd(&hist[(b << 16) + (key >> 16)], 1u);
        int p = atomicAdd(&vcnt[b], 1);
        if (p < VALIDCAP) vbuf[((size_t)b << 16) + p] = ((u64)key << 32) | (u32)(~n);
    }
}

/* 2: per-image cut bin: smallest bin such that suffix count >= TOPK (else 0) */
__global__ void k2_cut(const u32* __restrict__ hist, int* __restrict__ cut) {
    __shared__ u32 psum[256];
    int b = blockIdx.x, t = threadIdx.x;
    const u32* h = hist + ((size_t)b << 16);
    int hi = NBINS - t * 256;
    u32 s = 0;
    for (int i = hi - 256; i < hi; ++i) s += h[i];
    psum[t] = s;
    __syncthreads();
    if (t == 0) {
        u32 cumv = 0; int res = 0; bool found = false;
        for (int c = 0; c < 256 && !found; ++c) {
            u32 cs = psum[c];
            if (cumv + cs >= (u32)TOPK) {
                int top = NBINS - c * 256 - 1;
                for (int i = top; i > top - 256; --i) {
                    cumv += h[i];
                    if (cumv >= (u32)TOPK) { res = i; found = true; break; }
                }
            } else cumv += cs;
        }
        cut[b] = found ? res : 0;
    }
}

/* 3: gather candidates with bin >= cut */
__global__ void k3_gather(const u64* __restrict__ vbuf, const int* __restrict__ vcnt,
                          const int* __restrict__ cut, int* __restrict__ ccnt,
                          u64* __restrict__ cbuf) {
    int gid = blockIdx.x * blockDim.x + threadIdx.x;
    int b = gid >> 16, i = gid & 0xffff;
    int cnt = vcnt[b]; if (cnt > VALIDCAP) cnt = VALIDCAP;
    if (i < cnt) {
        u64 comp = vbuf[((size_t)b << 16) + i];
        if ((u32)(comp >> 48) >= (u32)cut[b]) {
            int p = atomicAdd(&ccnt[b], 1);
            if (p < CANDCAP) cbuf[b * CANDCAP + p] = comp;
        }
    }
}

/* 4: per-image bitonic sort (descending) of candidates in LDS */
__global__ __launch_bounds__(1024) void k4_sort(u64* __restrict__ cbuf,
                                                const int* __restrict__ ccnt,
                                                int* __restrict__ Mb) {
    __shared__ u64 buf[CANDCAP];
    int b = blockIdx.x, t = threadIdx.x;
    int cnt = ccnt[b]; if (cnt > CANDCAP) cnt = CANDCAP;
    for (int i = t; i < CANDCAP; i += 1024) buf[i] = (i < cnt) ? cbuf[b * CANDCAP + i] : 0ull;
    __syncthreads();
    for (int k = 2; k <= CANDCAP; k <<= 1)
        for (int j = k >> 1; j > 0; j >>= 1) {
            for (int i = t; i < CANDCAP; i += 1024) {
                int l = i ^ j;
                if (l > i) {
                    u64 a = buf[i], c = buf[l];
                    bool up = ((i & k) == 0);            /* descending network */
                    if (up ? (a < c) : (a > c)) { buf[i] = c; buf[l] = a; }
                }
            }
            __syncthreads();
        }
    for (int i = t; i < KCAP; i += 1024) cbuf[b * CANDCAP + i] = buf[i];
    if (t == 0) Mb[b] = cnt < TOPK ? cnt : TOPK;
}

/* 5: decode boxes, corners, area, score, argmax label for sorted top-M */
__global__ void k5_decode(const float* __restrict__ in, const u64* __restrict__ cbuf,
                          const int* __restrict__ Mb, float* __restrict__ det,
                          float4* __restrict__ cor, float* __restrict__ area) {
    int gid = blockIdx.x * blockDim.x + threadIdx.x;
    int b = gid >> 10, k = gid & 1023;
    if (b >= NB) return;
    if (k >= Mb[b]) return;
    u64 comp = cbuf[b * CANDCAP + k];
    u32 idx = ~(u32)comp;
    int a = idx % 9; int cell = idx / 9;
    int gj = cell & 127, gi = cell >> 7;
    float ci = (gi + 0.5f) * (1.0f / GH);
    float cj = (gj + 0.5f) * (1.0f / GW);
    const float SCL[3] = {0.5f, 1.0f, 2.0f};
    float s = SCL[a / 3], r = SCL[a % 3];
    float sq = sqrtf(r);
    float ah = (s * sq) * (4.0f / GH);
    float aw = (s / sq) * (4.0f / GW);
    const float* row = in + ((size_t)b * NANCH + idx) * NC;
    float t0 = row[0], t1 = row[1], t2 = row[2], t3 = row[3], scv = row[5];
    float di = ci + t0 * ah;
    float dj = cj + t1 * aw;
    float dh = ah * expf(t2);
    float dw = aw * expf(t3);
    float i0 = di - dh * 0.5f, j0 = dj - dw * 0.5f;
    float i1 = di + dh * 0.5f, j1 = dj + dw * 0.5f;
    float best = row[6]; int lab = 0;
    for (int c = 1; c < 80; ++c) { float v = row[6 + c]; if (v > best) { best = v; lab = c; } }
    float* d = det + (size_t)(b * KCAP + k) * 8;
    d[0] = di; d[1] = dj; d[2] = dh; d[3] = dw; d[4] = (float)lab; d[5] = scv;
    cor[b * KCAP + k] = make_float4(i0, j0, i1, j1);
    area[b * KCAP + k] = (i1 - i0) * (j1 - j0);
}

/* 6: IoU suppression bitmask, one wave per row i: bit j set iff iou>thr && j>i */
__global__ void k6_mask(const float4* __restrict__ cor, const float* __restrict__ area,
                        const int* __restrict__ Mb, u64* __restrict__ mask) {
    int wid = blockIdx.x * (blockDim.x >> 6) + (threadIdx.x >> 6);
    int lane = threadIdx.x & 63;
    int b = wid >> 10, i = wid & 1023;
    int m = Mb[b];
    if (i >= m) return;
    float4 bi = cor[b * KCAP + i]; float ai = area[b * KCAP + i];
    u64* rowp = mask + ((size_t)(b * KCAP + i)) * 16;
    for (int w = 0; w < 16; ++w) {
        int j = w * 64 + lane;
        bool pred = false;
        if (j > i && j < m) {
            float4 bj = cor[b * KCAP + j]; float aj = area[b * KCAP + j];
            float ti = fmaxf(bi.x, bj.x), tj = fmaxf(bi.y, bj.y);
            float b2 = fminf(bi.z, bj.z), b3 = fminf(bi.w, bj.w);
            float inter = fmaxf(b2 - ti, 0.0f) * fmaxf(b3 - tj, 0.0f);
            float uni = (ai + aj) - inter;
            float iou = inter / fmaxf(uni, 1e-12f);
            pred = iou > 0.75f;
        }
        u64 word = __ballot(pred);
        if (lane == w) rowp[w] = word;
    }
}

/* 7: serial greedy scan over bitmask, one wave per image */
__global__ void k7_scan(const u64* __restrict__ mask, const int* __restrict__ Mb,
                        u64* __restrict__ keep) {
    int b = blockIdx.x, lane = threadIdx.x;
    int m = Mb[b];
    const u64* mk = mask + (size_t)b * KCAP * 16;
    u64 supp = 0;                       /* lane w (<16) owns suppressed word w */
    for (int g = 0; g < 16; ++g) {
        u64 cur = shfl64(supp, g);      /* all lanes get suppressed word g */
        u64 keptW = 0;
        int base = g * 64;
        for (int t = 0; t < 64; ++t) {
            int i = base + t;
            if (i >= m) break;          /* uniform */
            if (!((cur >> t) & 1ull)) { /* kept */
                keptW |= 1ull << t;
                u64 rG = mk[(size_t)i * 16 + g];            /* broadcast addr */
                u64 rL = mk[(size_t)i * 16 + (lane & 15)];
                cur |= rG;              /* in-group suppression, replicated */
                if (lane < 16) supp |= rL;
            }
        }
        if (lane == 0) keep[b * 16 + g] = keptW;
    }
}

/* 8: rank kept bits, emit 100 rows per image (zero-padded) */
__global__ void k8_out(const u64* __restrict__ keep, const float* __restrict__ det,
                       float* __restrict__ out) {
    int b = blockIdx.x, t = threadIdx.x;
    __shared__ int cum[17];
    __shared__ u64 kw[16];
    if (t < 16) kw[t] = keep[b * 16 + t];
    __syncthreads();
    if (t == 0) {
        int c = 0;
        for (int w = 0; w < 16; ++w) { cum[w] = c; c += __builtin_popcountll(kw[w]); }
        cum[16] = c;
    }
    __syncthreads();
    int total = cum[16];
    if (t < 100) {
        float o0 = 0, o1 = 0, o2 = 0, o3 = 0, o4 = 0, o5 = 0;
        if (t < total) {
            int w = 0;
            while (w < 15 && cum[w + 1] <= t) w++;
            int j = t - cum[w];
            u64 word = kw[w];
            for (int q = 0; q < j; ++q) word &= word - 1;
            int pos = __builtin_ctzll(word);
            int c = w * 64 + pos;
            const float* d = det + (size_t)(b * KCAP + c) * 8;
            o0 = d[0]; o1 = d[1]; o2 = d[2]; o3 = d[3]; o4 = d[4]; o5 = d[5];
        }
        float* op = out + (size_t)b * 600 + (size_t)t * 6;
        op[0] = o0; op[1] = o1; op[2] = o2; op[3] = o3; op[4] = o4; op[5] = o5;
    }
}

extern "C" void kernel_launch(void* const* d_in, const int* in_sizes, int n_in,
                              void* d_out, int out_size, void* d_ws, size_t ws_size,
                              hipStream_t stream) {
    const float* in = (const float*)d_in[0];
    float* out = (float*)d_out;
    char* ws = (char*)d_ws;
    u32* hist  = (u32*)(ws + OFF_HIST);
    int* vcnt  = (int*)(ws + OFF_VCNT);
    int* ccnt  = (int*)(ws + OFF_CCNT);
    int* cut   = (int*)(ws + OFF_CUT);
    int* Mb    = (int*)(ws + OFF_M);
    u64* keep  = (u64*)(ws + OFF_KEEP);
    u64* vbuf  = (u64*)(ws + OFF_VBUF);
    u64* cbuf  = (u64*)(ws + OFF_CBUF);
    float* det = (float*)(ws + OFF_DET);
    float4* cor = (float4*)(ws + OFF_COR);
    float* area = (float*)(ws + OFF_AREA);
    u64* mask  = (u64*)(ws + OFF_MASK);

    hipMemsetAsync(ws, 0, MEMSET_BYTES, stream);
    k1_hist  <<<(NB * NANCH + 255) / 256, 256, 0, stream>>>(in, hist, vcnt, vbuf);
    k2_cut   <<<NB, 256, 0, stream>>>(hist, cut);
    k3_gather<<<(NB * VALIDCAP) / 256, 256, 0, stream>>>(vbuf, vcnt, cut, ccnt, cbuf);
    k4_sort  <<<NB, 1024, 0, stream>>>(cbuf, ccnt, Mb);
    k5_decode<<<(NB * KCAP) / 256, 256, 0, stream>>>(in, cbuf, Mb, det, cor, area);
    k6_mask  <<<(NB * KCAP) / 4, 256, 0, stream>>>(cor, area, Mb, mask);
    k7_scan  <<<NB, 64, 0, stream>>>(mask, Mb, keep);
    k8_out   <<<NB, 128, 0, stream>>>(keep, det, out);
}

// Round 2
// 1118.818 us; speedup vs baseline: 4.6088x; 4.6088x over previous
//
#include <hip/hip_runtime.h>
#include <cstdint>
#include <cstddef>

typedef unsigned int u32;
typedef unsigned long long u64;

#define NB 8
#define GH 128
#define GW 128
#define NA 9
#define NC 86
#define NANCH (GH*GW*NA)      /* 147456 */
#define BLOCKS_PER_IMG (NANCH/256)   /* 576 */
#define TOPK 1000
#define KCAP 1024
#define CANDCAP 4096
#define VALIDCAP 65536
#define NBINS 65536

/* ---- workspace layout (bytes) ---- */
#define OFF_HIST      ((size_t)0)
#define SZ_HIST       ((size_t)NB*NBINS*4)            /* 2,097,152 */
#define OFF_VCNT      (OFF_HIST + SZ_HIST)
#define OFF_CCNT      (OFF_VCNT + 32)
#define MEMSET_BYTES  (OFF_CCNT + 32)                 /* zero hist + counters */
#define OFF_CUT       (MEMSET_BYTES)
#define OFF_M         (OFF_CUT + 32)
#define OFF_KEEP      (OFF_M + 32)                    /* NB*16*8 = 1024 */
#define OFF_VBUF      (OFF_KEEP + 1024)
#define SZ_VBUF       ((size_t)NB*VALIDCAP*8)
#define OFF_CBUF      (OFF_VBUF + SZ_VBUF)
#define SZ_CBUF       ((size_t)NB*CANDCAP*8)
#define OFF_DET       (OFF_CBUF + SZ_CBUF)
#define SZ_DET        ((size_t)NB*KCAP*8*4)
#define OFF_COR       (OFF_DET + SZ_DET)
#define SZ_COR        ((size_t)NB*KCAP*16)
#define OFF_AREA      (OFF_COR + SZ_COR)
#define SZ_AREA       ((size_t)NB*KCAP*4)
#define OFF_MASK      (OFF_AREA + SZ_AREA)
#define SZ_MASK       ((size_t)NB*KCAP*16*8)

__device__ __forceinline__ u64 shfl64(u64 v, int src) {
    int lo = __shfl((int)(v & 0xffffffffull), src, 64);
    int hi = __shfl((int)(v >> 32), src, 64);
    return ((u64)(u32)hi << 32) | (u32)lo;
}

/* 1: strided score scan -> histogram + valid (key,~idx) compaction.
   vcnt atomic is block-aggregated: wave ballot prefix -> LDS -> ONE global
   atomicAdd per block (was: one per valid thread on 8 addresses = 4 ms). */
__global__ __launch_bounds__(256) void k1_hist(const float* __restrict__ in,
                        u32* __restrict__ hist,
                        int* __restrict__ vcnt, u64* __restrict__ vbuf) {
    __shared__ int wcnt[4];
    __shared__ int woff[4];
    __shared__ int blockbase;
    int gid = blockIdx.x * 256 + threadIdx.x;          /* grid exact, no bounds */
    int b = blockIdx.x / BLOCKS_PER_IMG;               /* block within one image */
    int lane = threadIdx.x & 63;
    int wv = threadIdx.x >> 6;
    float sc = in[(size_t)gid * NC + 5];
    bool valid = (sc >= 0.5f);
    u32 key = 0;
    if (valid) {
        key = __float_as_uint(sc) ^ 0x80000000u;       /* positive floats: monotone */
        atomicAdd(&hist[(b << 16) + (key >> 16)], 1u); /* ~400 bins/img: pipelined */
    }
    u64 mask = __ballot(valid);
    if (lane == 0) wcnt[wv] = __popcll(mask);
    __syncthreads();
    if (threadIdx.x == 0) {
        int c0 = wcnt[0], c1 = wcnt[1], c2 = wcnt[2], c3 = wcnt[3];
        woff[0] = 0; woff[1] = c0; woff[2] = c0 + c1; woff[3] = c0 + c1 + c2;
        blockbase = atomicAdd(&vcnt[b], c0 + c1 + c2 + c3);
    }
    __syncthreads();
    if (valid) {
        int prefix = __popcll(mask & ((1ull << lane) - 1ull));
        int p = blockbase + woff[wv] + prefix;
        u32 n = (u32)(gid - b * NANCH);
        if (p < VALIDCAP) vbuf[((size_t)b << 16) + p] = ((u64)key << 32) | (u32)(~n);
    }
}

/* 2: per-image cut bin: smallest bin such that suffix count >= TOPK (else 0) */
__global__ void k2_cut(const u32* __restrict__ hist, int* __restrict__ cut) {
    __shared__ u32 psum[256];
    int b = blockIdx.x, t = threadIdx.x;
    const u32* h = hist + ((size_t)b << 16);
    int hi = NBINS - t * 256;
    u32 s = 0;
    for (int i = hi - 256; i < hi; ++i) s += h[i];
    psum[t] = s;
    __syncthreads();
    if (t == 0) {
        u32 cumv = 0; int res = 0; bool found = false;
        for (int c = 0; c < 256 && !found; ++c) {
            u32 cs = psum[c];
            if (cumv + cs >= (u32)TOPK) {
                int top = NBINS - c * 256 - 1;
                for (int i = top; i > top - 256; --i) {
                    cumv += h[i];
                    if (cumv >= (u32)TOPK) { res = i; found = true; break; }
                }
            } else cumv += cs;
        }
        cut[b] = found ? res : 0;
    }
}

/* 3: gather candidates with bin >= cut */
__global__ void k3_gather(const u64* __restrict__ vbuf, const int* __restrict__ vcnt,
                          const int* __restrict__ cut, int* __restrict__ ccnt,
                          u64* __restrict__ cbuf) {
    int gid = blockIdx.x * blockDim.x + threadIdx.x;
    int b = gid >> 16, i = gid & 0xffff;
    int cnt = vcnt[b]; if (cnt > VALIDCAP) cnt = VALIDCAP;
    if (i < cnt) {
        u64 comp = vbuf[((size_t)b << 16) + i];
        if ((u32)(comp >> 48) >= (u32)cut[b]) {
            int p = atomicAdd(&ccnt[b], 1);
            if (p < CANDCAP) cbuf[b * CANDCAP + p] = comp;
        }
    }
}

/* 4: per-image bitonic sort (descending) of candidates in LDS */
__global__ __launch_bounds__(1024) void k4_sort(u64* __restrict__ cbuf,
                                                const int* __restrict__ ccnt,
                                                int* __restrict__ Mb) {
    __shared__ u64 buf[CANDCAP];
    int b = blockIdx.x, t = threadIdx.x;
    int cnt = ccnt[b]; if (cnt > CANDCAP) cnt = CANDCAP;
    for (int i = t; i < CANDCAP; i += 1024) buf[i] = (i < cnt) ? cbuf[b * CANDCAP + i] : 0ull;
    __syncthreads();
    for (int k = 2; k <= CANDCAP; k <<= 1)
        for (int j = k >> 1; j > 0; j >>= 1) {
            for (int i = t; i < CANDCAP; i += 1024) {
                int l = i ^ j;
                if (l > i) {
                    u64 a = buf[i], c = buf[l];
                    bool up = ((i & k) == 0);            /* descending network */
                    if (up ? (a < c) : (a > c)) { buf[i] = c; buf[l] = a; }
                }
            }
            __syncthreads();
        }
    for (int i = t; i < KCAP; i += 1024) cbuf[b * CANDCAP + i] = buf[i];
    if (t == 0) Mb[b] = cnt < TOPK ? cnt : TOPK;
}

/* 5: decode boxes, corners, area, score, argmax label for sorted top-M */
__global__ void k5_decode(const float* __restrict__ in, const u64* __restrict__ cbuf,
                          const int* __restrict__ Mb, float* __restrict__ det,
                          float4* __restrict__ cor, float* __restrict__ area) {
    int gid = blockIdx.x * blockDim.x + threadIdx.x;
    int b = gid >> 10, k = gid & 1023;
    if (b >= NB) return;
    if (k >= Mb[b]) return;
    u64 comp = cbuf[b * CANDCAP + k];
    u32 idx = ~(u32)comp;
    int a = idx % 9; int cell = idx / 9;
    int gj = cell & 127, gi = cell >> 7;
    float ci = (gi + 0.5f) * (1.0f / GH);
    float cj = (gj + 0.5f) * (1.0f / GW);
    const float SCL[3] = {0.5f, 1.0f, 2.0f};
    float s = SCL[a / 3], r = SCL[a % 3];
    float sq = sqrtf(r);
    float ah = (s * sq) * (4.0f / GH);
    float aw = (s / sq) * (4.0f / GW);
    const float* row = in + ((size_t)b * NANCH + idx) * NC;
    float t0 = row[0], t1 = row[1], t2 = row[2], t3 = row[3], scv = row[5];
    float di = ci + t0 * ah;
    float dj = cj + t1 * aw;
    float dh = ah * expf(t2);
    float dw = aw * expf(t3);
    float i0 = di - dh * 0.5f, j0 = dj - dw * 0.5f;
    float i1 = di + dh * 0.5f, j1 = dj + dw * 0.5f;
    float best = row[6]; int lab = 0;
    for (int c = 1; c < 80; ++c) { float v = row[6 + c]; if (v > best) { best = v; lab = c; } }
    float* d = det + (size_t)(b * KCAP + k) * 8;
    d[0] = di; d[1] = dj; d[2] = dh; d[3] = dw; d[4] = (float)lab; d[5] = scv;
    cor[b * KCAP + k] = make_float4(i0, j0, i1, j1);
    area[b * KCAP + k] = (i1 - i0) * (j1 - j0);
}

/* 6: IoU suppression bitmask, one wave per row i: bit j set iff iou>thr && j>i */
__global__ void k6_mask(const float4* __restrict__ cor, const float* __restrict__ area,
                        const int* __restrict__ Mb, u64* __restrict__ mask) {
    int wid = blockIdx.x * (blockDim.x >> 6) + (threadIdx.x >> 6);
    int lane = threadIdx.x & 63;
    int b = wid >> 10, i = wid & 1023;
    int m = Mb[b];
    if (i >= m) return;
    float4 bi = cor[b * KCAP + i]; float ai = area[b * KCAP + i];
    u64* rowp = mask + ((size_t)(b * KCAP + i)) * 16;
    for (int w = 0; w < 16; ++w) {
        int j = w * 64 + lane;
        bool pred = false;
        if (j > i && j < m) {
            float4 bj = cor[b * KCAP + j]; float aj = area[b * KCAP + j];
            float ti = fmaxf(bi.x, bj.x), tj = fmaxf(bi.y, bj.y);
            float b2 = fminf(bi.z, bj.z), b3 = fminf(bi.w, bj.w);
            float inter = fmaxf(b2 - ti, 0.0f) * fmaxf(b3 - tj, 0.0f);
            float uni = (ai + aj) - inter;
            float iou = inter / fmaxf(uni, 1e-12f);
            pred = iou > 0.75f;
        }
        u64 word = __ballot(pred);
        if (lane == w) rowp[w] = word;
    }
}

/* 7: serial greedy scan over bitmask, one wave per image */
__global__ void k7_scan(const u64* __restrict__ mask, const int* __restrict__ Mb,
                        u64* __restrict__ keep) {
    int b = blockIdx.x, lane = threadIdx.x;
    int m = Mb[b];
    const u64* mk = mask + (size_t)b * KCAP * 16;
    u64 supp = 0;                       /* lane w (<16) owns suppressed word w */
    for (int g = 0; g < 16; ++g) {
        u64 cur = shfl64(supp, g);      /* all lanes get suppressed word g */
        u64 keptW = 0;
        int base = g * 64;
        for (int t = 0; t < 64; ++t) {
            int i = base + t;
            if (i >= m) break;          /* uniform */
            if (!((cur >> t) & 1ull)) { /* kept */
                keptW |= 1ull << t;
                u64 rG = mk[(size_t)i * 16 + g];            /* broadcast addr */
                u64 rL = mk[(size_t)i * 16 + (lane & 15)];
                cur |= rG;              /* in-group suppression, replicated */
                if (lane < 16) supp |= rL;
            }
        }
        if (lane == 0) keep[b * 16 + g] = keptW;
    }
}

/* 8: rank kept bits, emit 100 rows per image (zero-padded) */
__global__ void k8_out(const u64* __restrict__ keep, const float* __restrict__ det,
                       float* __restrict__ out) {
    int b = blockIdx.x, t = threadIdx.x;
    __shared__ int cum[17];
    __shared__ u64 kw[16];
    if (t < 16) kw[t] = keep[b * 16 + t];
    __syncthreads();
    if (t == 0) {
        int c = 0;
        for (int w = 0; w < 16; ++w) { cum[w] = c; c += __builtin_popcountll(kw[w]); }
        cum[16] = c;
    }
    __syncthreads();
    int total = cum[16];
    if (t < 100) {
        float o0 = 0, o1 = 0, o2 = 0, o3 = 0, o4 = 0, o5 = 0;
        if (t < total) {
            int w = 0;
            while (w < 15 && cum[w + 1] <= t) w++;
            int j = t - cum[w];
            u64 word = kw[w];
            for (int q = 0; q < j; ++q) word &= word - 1;
            int pos = __builtin_ctzll(word);
            int c = w * 64 + pos;
            const float* d = det + (size_t)(b * KCAP + c) * 8;
            o0 = d[0]; o1 = d[1]; o2 = d[2]; o3 = d[3]; o4 = d[4]; o5 = d[5];
        }
        float* op = out + (size_t)b * 600 + (size_t)t * 6;
        op[0] = o0; op[1] = o1; op[2] = o2; op[3] = o3; op[4] = o4; op[5] = o5;
    }
}

extern "C" void kernel_launch(void* const* d_in, const int* in_sizes, int n_in,
                              void* d_out, int out_size, void* d_ws, size_t ws_size,
                              hipStream_t stream) {
    const float* in = (const float*)d_in[0];
    float* out = (float*)d_out;
    char* ws = (char*)d_ws;
    u32* hist  = (u32*)(ws + OFF_HIST);
    int* vcnt  = (int*)(ws + OFF_VCNT);
    int* ccnt  = (int*)(ws + OFF_CCNT);
    int* cut   = (int*)(ws + OFF_CUT);
    int* Mb    = (int*)(ws + OFF_M);
    u64* keep  = (u64*)(ws + OFF_KEEP);
    u64* vbuf  = (u64*)(ws + OFF_VBUF);
    u64* cbuf  = (u64*)(ws + OFF_CBUF);
    float* det = (float*)(ws + OFF_DET);
    float4* cor = (float4*)(ws + OFF_COR);
    float* area = (float*)(ws + OFF_AREA);
    u64* mask  = (u64*)(ws + OFF_MASK);

    hipMemsetAsync(ws, 0, MEMSET_BYTES, stream);
    k1_hist  <<<(NB * NANCH) / 256, 256, 0, stream>>>(in, hist, vcnt, vbuf);
    k2_cut   <<<NB, 256, 0, stream>>>(hist, cut);
    k3_gather<<<(NB * VALIDCAP) / 256, 256, 0, stream>>>(vbuf, vcnt, cut, ccnt, cbuf);
    k4_sort  <<<NB, 1024, 0, stream>>>(cbuf, ccnt, Mb);
    k5_decode<<<(NB * KCAP) / 256, 256, 0, stream>>>(in, cbuf, Mb, det, cor, area);
    k6_mask  <<<(NB * KCAP) / 4, 256, 0, stream>>>(cor, area, Mb, mask);
    k7_scan  <<<NB, 64, 0, stream>>>(mask, Mb, keep);
    k8_out   <<<NB, 128, 0, stream>>>(keep, det, out);
}

// Round 3
// 706.254 us; speedup vs baseline: 7.3011x; 1.5842x over previous
//
#include <hip/hip_runtime.h>
#include <cstdint>
#include <cstddef>

typedef unsigned int u32;
typedef unsigned long long u64;

#define NB 8
#define GH 128
#define GW 128
#define NA 9
#define NC 86
#define NANCH (GH*GW*NA)      /* 147456 */
#define BLOCKS_PER_IMG (NANCH/256)   /* 576 */
#define TOPK 1000
#define KCAP 1024
#define CANDCAP 4096
#define VALIDCAP 65536
#define NBINS 65536

/* ---- workspace layout (bytes) ---- */
#define OFF_HIST      ((size_t)0)
#define SZ_HIST       ((size_t)NB*NBINS*4)            /* 2,097,152 */
#define OFF_VCNT      (OFF_HIST + SZ_HIST)
#define OFF_CCNT      (OFF_VCNT + 32)
#define MEMSET_BYTES  (OFF_CCNT + 32)                 /* zero hist + counters */
#define OFF_CUT       (MEMSET_BYTES)
#define OFF_M         (OFF_CUT + 32)
#define OFF_KEEP      (OFF_M + 32)                    /* NB*16*8 = 1024 */
#define OFF_VBUF      (OFF_KEEP + 1024)
#define SZ_VBUF       ((size_t)NB*VALIDCAP*8)
#define OFF_CBUF      (OFF_VBUF + SZ_VBUF)
#define SZ_CBUF       ((size_t)NB*CANDCAP*8)
#define OFF_DET       (OFF_CBUF + SZ_CBUF)
#define SZ_DET        ((size_t)NB*KCAP*8*4)
#define OFF_COR       (OFF_DET + SZ_DET)
#define SZ_COR        ((size_t)NB*KCAP*16)
#define OFF_AREA      (OFF_COR + SZ_COR)
#define SZ_AREA       ((size_t)NB*KCAP*4)
#define OFF_MASK      (OFF_AREA + SZ_AREA)
#define SZ_MASK       ((size_t)NB*KCAP*16*8)

__device__ __forceinline__ u64 shfl64(u64 v, int src) {
    int lo = __shfl((int)(v & 0xffffffffull), src, 64);
    int hi = __shfl((int)(v >> 32), src, 64);
    return ((u64)(u32)hi << 32) | (u32)lo;
}
__device__ __forceinline__ u64 shfl64_xor(u64 v, int m) {
    int lo = __shfl_xor((int)(v & 0xffffffffull), m, 64);
    int hi = __shfl_xor((int)(v >> 32), m, 64);
    return ((u64)(u32)hi << 32) | (u32)lo;
}
__device__ __forceinline__ u64 readlane64(u64 v, int lane) {
    int lo = __builtin_amdgcn_readlane((int)(v & 0xffffffffull), lane);
    int hi = __builtin_amdgcn_readlane((int)(v >> 32), lane);
    return ((u64)(u32)hi << 32) | (u32)lo;
}

/* 1: strided score scan -> histogram + valid (key,~idx) compaction.
   vcnt atomic is block-aggregated: wave ballot prefix -> LDS -> ONE global
   atomicAdd per block (was: one per valid thread on 8 addresses = 4 ms). */
__global__ __launch_bounds__(256) void k1_hist(const float* __restrict__ in,
                        u32* __restrict__ hist,
                        int* __restrict__ vcnt, u64* __restrict__ vbuf) {
    __shared__ int wcnt[4];
    __shared__ int woff[4];
    __shared__ int blockbase;
    int gid = blockIdx.x * 256 + threadIdx.x;          /* grid exact, no bounds */
    int b = blockIdx.x / BLOCKS_PER_IMG;               /* block within one image */
    int lane = threadIdx.x & 63;
    int wv = threadIdx.x >> 6;
    float sc = in[(size_t)gid * NC + 5];
    bool valid = (sc >= 0.5f);
    u32 key = 0;
    if (valid) {
        key = __float_as_uint(sc) ^ 0x80000000u;       /* positive floats: monotone */
        atomicAdd(&hist[(b << 16) + (key >> 16)], 1u); /* ~400 bins/img: pipelined */
    }
    u64 mask = __ballot(valid);
    if (lane == 0) wcnt[wv] = __popcll(mask);
    __syncthreads();
    if (threadIdx.x == 0) {
        int c0 = wcnt[0], c1 = wcnt[1], c2 = wcnt[2], c3 = wcnt[3];
        woff[0] = 0; woff[1] = c0; woff[2] = c0 + c1; woff[3] = c0 + c1 + c2;
        blockbase = atomicAdd(&vcnt[b], c0 + c1 + c2 + c3);
    }
    __syncthreads();
    if (valid) {
        int prefix = __popcll(mask & ((1ull << lane) - 1ull));
        int p = blockbase + woff[wv] + prefix;
        u32 n = (u32)(gid - b * NANCH);
        if (p < VALIDCAP) vbuf[((size_t)b << 16) + p] = ((u64)key << 32) | (u32)(~n);
    }
}

/* 2: per-image cut bin: smallest bin such that suffix count >= TOPK (else 0) */
__global__ void k2_cut(const u32* __restrict__ hist, int* __restrict__ cut) {
    __shared__ u32 psum[256];
    int b = blockIdx.x, t = threadIdx.x;
    const u32* h = hist + ((size_t)b << 16);
    int hi = NBINS - t * 256;
    u32 s = 0;
    for (int i = hi - 256; i < hi; ++i) s += h[i];
    psum[t] = s;
    __syncthreads();
    if (t == 0) {
        u32 cumv = 0; int res = 0; bool found = false;
        for (int c = 0; c < 256 && !found; ++c) {
            u32 cs = psum[c];
            if (cumv + cs >= (u32)TOPK) {
                int top = NBINS - c * 256 - 1;
                for (int i = top; i > top - 256; --i) {
                    cumv += h[i];
                    if (cumv >= (u32)TOPK) { res = i; found = true; break; }
                }
            } else cumv += cs;
        }
        cut[b] = found ? res : 0;
    }
}

/* 3: gather candidates with bin >= cut — block-aggregated atomic (one per
   block, was one per candidate on 8 addresses = serialized L2 round-trips) */
__global__ __launch_bounds__(256) void k3_gather(const u64* __restrict__ vbuf,
                          const int* __restrict__ vcnt,
                          const int* __restrict__ cut, int* __restrict__ ccnt,
                          u64* __restrict__ cbuf) {
    __shared__ int wcnt[4];
    __shared__ int woff[4];
    __shared__ int blockbase;
    int gid = blockIdx.x * 256 + threadIdx.x;
    int b = gid >> 16, i = gid & 0xffff;               /* 256 blocks per image */
    int lane = threadIdx.x & 63;
    int wv = threadIdx.x >> 6;
    int cnt = vcnt[b]; if (cnt > VALIDCAP) cnt = VALIDCAP;
    bool take = false; u64 comp = 0;
    if (i < cnt) {
        comp = vbuf[((size_t)b << 16) + i];
        take = ((u32)(comp >> 48) >= (u32)cut[b]);
    }
    u64 mask = __ballot(take);
    if (lane == 0) wcnt[wv] = __popcll(mask);
    __syncthreads();
    if (threadIdx.x == 0) {
        int c0 = wcnt[0], c1 = wcnt[1], c2 = wcnt[2], c3 = wcnt[3];
        woff[0] = 0; woff[1] = c0; woff[2] = c0 + c1; woff[3] = c0 + c1 + c2;
        blockbase = (c0 + c1 + c2 + c3) ? atomicAdd(&ccnt[b], c0 + c1 + c2 + c3) : 0;
    }
    __syncthreads();
    if (take) {
        int p = blockbase + woff[wv] + __popcll(mask & ((1ull << lane) - 1ull));
        if (p < CANDCAP) cbuf[b * CANDCAP + p] = comp;
    }
}

/* 4: per-image bitonic sort (descending) of candidates in LDS */
__global__ __launch_bounds__(1024) void k4_sort(u64* __restrict__ cbuf,
                                                const int* __restrict__ ccnt,
                                                int* __restrict__ Mb) {
    __shared__ u64 buf[CANDCAP];
    int b = blockIdx.x, t = threadIdx.x;
    int cnt = ccnt[b]; if (cnt > CANDCAP) cnt = CANDCAP;
    for (int i = t; i < CANDCAP; i += 1024) buf[i] = (i < cnt) ? cbuf[b * CANDCAP + i] : 0ull;
    __syncthreads();
    for (int k = 2; k <= CANDCAP; k <<= 1)
        for (int j = k >> 1; j > 0; j >>= 1) {
            for (int i = t; i < CANDCAP; i += 1024) {
                int l = i ^ j;
                if (l > i) {
                    u64 a = buf[i], c = buf[l];
                    bool up = ((i & k) == 0);            /* descending network */
                    if (up ? (a < c) : (a > c)) { buf[i] = c; buf[l] = a; }
                }
            }
            __syncthreads();
        }
    for (int i = t; i < KCAP; i += 1024) cbuf[b * CANDCAP + i] = buf[i];
    if (t == 0) Mb[b] = cnt < TOPK ? cnt : TOPK;
}

/* 5: decode boxes, corners, area, score, argmax label for sorted top-M */
__global__ void k5_decode(const float* __restrict__ in, const u64* __restrict__ cbuf,
                          const int* __restrict__ Mb, float* __restrict__ det,
                          float4* __restrict__ cor, float* __restrict__ area) {
    int gid = blockIdx.x * blockDim.x + threadIdx.x;
    int b = gid >> 10, k = gid & 1023;
    if (b >= NB) return;
    if (k >= Mb[b]) return;
    u64 comp = cbuf[b * CANDCAP + k];
    u32 idx = ~(u32)comp;
    int a = idx % 9; int cell = idx / 9;
    int gj = cell & 127, gi = cell >> 7;
    float ci = (gi + 0.5f) * (1.0f / GH);
    float cj = (gj + 0.5f) * (1.0f / GW);
    const float SCL[3] = {0.5f, 1.0f, 2.0f};
    float s = SCL[a / 3], r = SCL[a % 3];
    float sq = sqrtf(r);
    float ah = (s * sq) * (4.0f / GH);
    float aw = (s / sq) * (4.0f / GW);
    const float* row = in + ((size_t)b * NANCH + idx) * NC;
    float t0 = row[0], t1 = row[1], t2 = row[2], t3 = row[3], scv = row[5];
    float di = ci + t0 * ah;
    float dj = cj + t1 * aw;
    float dh = ah * expf(t2);
    float dw = aw * expf(t3);
    float i0 = di - dh * 0.5f, j0 = dj - dw * 0.5f;
    float i1 = di + dh * 0.5f, j1 = dj + dw * 0.5f;
    float best = row[6]; int lab = 0;
    for (int c = 1; c < 80; ++c) { float v = row[6 + c]; if (v > best) { best = v; lab = c; } }
    float* d = det + (size_t)(b * KCAP + k) * 8;
    d[0] = di; d[1] = dj; d[2] = dh; d[3] = dw; d[4] = (float)lab; d[5] = scv;
    cor[b * KCAP + k] = make_float4(i0, j0, i1, j1);
    area[b * KCAP + k] = (i1 - i0) * (j1 - j0);
}

/* 6: IoU suppression bitmask, one wave per row i: bit j set iff iou>thr && j>i */
__global__ void k6_mask(const float4* __restrict__ cor, const float* __restrict__ area,
                        const int* __restrict__ Mb, u64* __restrict__ mask) {
    int wid = blockIdx.x * (blockDim.x >> 6) + (threadIdx.x >> 6);
    int lane = threadIdx.x & 63;
    int b = wid >> 10, i = wid & 1023;
    int m = Mb[b];
    if (i >= m) return;
    float4 bi = cor[b * KCAP + i]; float ai = area[b * KCAP + i];
    u64* rowp = mask + ((size_t)(b * KCAP + i)) * 16;
    for (int w = 0; w < 16; ++w) {
        int j = w * 64 + lane;
        bool pred = false;
        if (j > i && j < m) {
            float4 bj = cor[b * KCAP + j]; float aj = area[b * KCAP + j];
            float ti = fmaxf(bi.x, bj.x), tj = fmaxf(bi.y, bj.y);
            float b2 = fminf(bi.z, bj.z), b3 = fminf(bi.w, bj.w);
            float inter = fmaxf(b2 - ti, 0.0f) * fmaxf(b3 - tj, 0.0f);
            float uni = (ai + aj) - inter;
            float iou = inter / fmaxf(uni, 1e-12f);
            pred = iou > 0.75f;
        }
        u64 word = __ballot(pred);
        if (lane == w) rowp[w] = word;
    }
}

/* 7: serial greedy scan — register/readlane recurrence, pipelined prefetch.
   Critical chain per group: ~1 global latency + 64 scalar steps (was: one
   dependent HBM load per kept box = ~400 us). */
__global__ __launch_bounds__(64) void k7_scan(const u64* __restrict__ mask,
                        const int* __restrict__ Mb, u64* __restrict__ keep) {
    int b = blockIdx.x, lane = threadIdx.x;
    int m = Mb[b];
    const u64* mk = mask + (size_t)b * KCAP * 16;
    int myw = lane & 15;              /* word this lane ORs in cross-group */
    int myq = lane >> 4;              /* row quarter (16 rows) */
    u64 supp = 0;                     /* lane w<16 owns suppressed word w */

    /* prefetch group 0 in-group column: lane t -> mask[t][0] */
    int r0 = lane;
    u64 colW = (r0 < m) ? mk[(size_t)r0 * 16 + 0] : 0ull;

    for (int g = 0; g < 16; ++g) {
        u64 rowW = colW;
        /* prefetch next group's column (independent; overlaps scalar loop) */
        if (g + 1 < 16) {
            int rn = (g + 1) * 64 + lane;
            colW = (rn < m) ? mk[(size_t)rn * 16 + (g + 1)] : 0ull;
        }
        u64 cur = shfl64(supp, g);    /* suppressed bits for this group */
        int lim = m - g * 64;         /* valid rows in this group (may be <=0) */
        u64 keptW = 0;
        #pragma unroll
        for (int t = 0; t < 64; ++t) {
            u64 w = readlane64(rowW, t);                 /* off critical chain */
            bool kept = (t < lim) && !((cur >> t) & 1ull); /* uniform */
            if (kept) { keptW |= (1ull << t); cur |= w; }
        }
        if (lane == 0) keep[b * 16 + g] = keptW;
        /* cross-group OR: lane (myw,myq) ORs word myw over its 16 kept rows */
        u64 acc = 0;
        #pragma unroll
        for (int s = 0; s < 16; ++s) {
            int t = myq * 16 + s;
            if ((keptW >> t) & 1ull)
                acc |= mk[(size_t)(g * 64 + t) * 16 + myw];
        }
        acc |= shfl64_xor(acc, 16);
        acc |= shfl64_xor(acc, 32);
        if (lane < 16) supp |= acc;
    }
}

/* 8: rank kept bits, emit 100 rows per image (zero-padded) */
__global__ void k8_out(const u64* __restrict__ keep, const float* __restrict__ det,
                       float* __restrict__ out) {
    int b = blockIdx.x, t = threadIdx.x;
    __shared__ int cum[17];
    __shared__ u64 kw[16];
    if (t < 16) kw[t] = keep[b * 16 + t];
    __syncthreads();
    if (t == 0) {
        int c = 0;
        for (int w = 0; w < 16; ++w) { cum[w] = c; c += __builtin_popcountll(kw[w]); }
        cum[16] = c;
    }
    __syncthreads();
    int total = cum[16];
    if (t < 100) {
        float o0 = 0, o1 = 0, o2 = 0, o3 = 0, o4 = 0, o5 = 0;
        if (t < total) {
            int w = 0;
            while (w < 15 && cum[w + 1] <= t) w++;
            int j = t - cum[w];
            u64 word = kw[w];
            for (int q = 0; q < j; ++q) word &= word - 1;
            int pos = __builtin_ctzll(word);
            int c = w * 64 + pos;
            const float* d = det + (size_t)(b * KCAP + c) * 8;
            o0 = d[0]; o1 = d[1]; o2 = d[2]; o3 = d[3]; o4 = d[4]; o5 = d[5];
        }
        float* op = out + (size_t)b * 600 + (size_t)t * 6;
        op[0] = o0; op[1] = o1; op[2] = o2; op[3] = o3; op[4] = o4; op[5] = o5;
    }
}

extern "C" void kernel_launch(void* const* d_in, const int* in_sizes, int n_in,
                              void* d_out, int out_size, void* d_ws, size_t ws_size,
                              hipStream_t stream) {
    const float* in = (const float*)d_in[0];
    float* out = (float*)d_out;
    char* ws = (char*)d_ws;
    u32* hist  = (u32*)(ws + OFF_HIST);
    int* vcnt  = (int*)(ws + OFF_VCNT);
    int* ccnt  = (int*)(ws + OFF_CCNT);
    int* cut   = (int*)(ws + OFF_CUT);
    int* Mb    = (int*)(ws + OFF_M);
    u64* keep  = (u64*)(ws + OFF_KEEP);
    u64* vbuf  = (u64*)(ws + OFF_VBUF);
    u64* cbuf  = (u64*)(ws + OFF_CBUF);
    float* det = (float*)(ws + OFF_DET);
    float4* cor = (float4*)(ws + OFF_COR);
    float* area = (float*)(ws + OFF_AREA);
    u64* mask  = (u64*)(ws + OFF_MASK);

    hipMemsetAsync(ws, 0, MEMSET_BYTES, stream);
    k1_hist  <<<(NB * NANCH) / 256, 256, 0, stream>>>(in, hist, vcnt, vbuf);
    k2_cut   <<<NB, 256, 0, stream>>>(hist, cut);
    k3_gather<<<(NB * VALIDCAP) / 256, 256, 0, stream>>>(vbuf, vcnt, cut, ccnt, cbuf);
    k4_sort  <<<NB, 1024, 0, stream>>>(cbuf, ccnt, Mb);
    k5_decode<<<(NB * KCAP) / 256, 256, 0, stream>>>(in, cbuf, Mb, det, cor, area);
    k6_mask  <<<(NB * KCAP) / 4, 256, 0, stream>>>(cor, area, Mb, mask);
    k7_scan  <<<NB, 64, 0, stream>>>(mask, Mb, keep);
    k8_out   <<<NB, 128, 0, stream>>>(keep, det, out);
}

// Round 4
// 680.659 us; speedup vs baseline: 7.5757x; 1.0376x over previous
//
#include <hip/hip_runtime.h>
#include <cstdint>
#include <cstddef>

typedef unsigned int u32;
typedef unsigned long long u64;

#define NB 8
#define GH 128
#define GW 128
#define NA 9
#define NC 86
#define NANCH (GH*GW*NA)      /* 147456 */
#define BLOCKS_PER_IMG (NANCH/256)   /* 576 */
#define TOPK 1000
#define KCAP 1024
#define CANDCAP 2048
#define VALIDCAP 65536
#define HBINS 1024            /* scores>=0.5 -> key>>16 in [48896, ~49344] */
#define HBASE 48896u

/* ---- workspace layout (bytes) ---- */
#define OFF_HIST      ((size_t)0)
#define SZ_HIST       ((size_t)NB*HBINS*4)            /* 32 KB */
#define OFF_VCNT      (OFF_HIST + SZ_HIST)
#define OFF_CCNT      (OFF_VCNT + 32)
#define MEMSET_BYTES  (OFF_CCNT + 32)                 /* zero hist + counters */
#define OFF_CUT       (MEMSET_BYTES)
#define OFF_M         (OFF_CUT + 32)
#define OFF_VBUF      (OFF_M + 32)
#define SZ_VBUF       ((size_t)NB*VALIDCAP*8)
#define OFF_CBUF      (OFF_VBUF + SZ_VBUF)
#define SZ_CBUF       ((size_t)NB*CANDCAP*8)
#define OFF_DET       (OFF_CBUF + SZ_CBUF)
#define SZ_DET        ((size_t)NB*KCAP*8*4)
#define OFF_COR       (OFF_DET + SZ_DET)
#define SZ_COR        ((size_t)NB*KCAP*16)
#define OFF_AREA      (OFF_COR + SZ_COR)
#define SZ_AREA       ((size_t)NB*KCAP*4)
#define OFF_MASK      (OFF_AREA + SZ_AREA)
#define SZ_MASK       ((size_t)NB*KCAP*16*8)

__device__ __forceinline__ u64 shfl64(u64 v, int src) {
    int lo = __shfl((int)(v & 0xffffffffull), src, 64);
    int hi = __shfl((int)(v >> 32), src, 64);
    return ((u64)(u32)hi << 32) | (u32)lo;
}
__device__ __forceinline__ u64 shfl64_xor(u64 v, int m) {
    int lo = __shfl_xor((int)(v & 0xffffffffull), m, 64);
    int hi = __shfl_xor((int)(v >> 32), m, 64);
    return ((u64)(u32)hi << 32) | (u32)lo;
}
__device__ __forceinline__ u64 readlane64(u64 v, int lane) {
    int lo = __builtin_amdgcn_readlane((int)(v & 0xffffffffull), lane);
    int hi = __builtin_amdgcn_readlane((int)(v >> 32), lane);
    return ((u64)(u32)hi << 32) | (u32)lo;
}

/* 1: strided score scan -> small histogram + valid (key,~idx) compaction. */
__global__ __launch_bounds__(256) void k1_hist(const float* __restrict__ in,
                        u32* __restrict__ hist,
                        int* __restrict__ vcnt, u64* __restrict__ vbuf) {
    __shared__ int wcnt[4];
    __shared__ int woff[4];
    __shared__ int blockbase;
    int gid = blockIdx.x * 256 + threadIdx.x;
    int b = blockIdx.x / BLOCKS_PER_IMG;
    int lane = threadIdx.x & 63;
    int wv = threadIdx.x >> 6;
    float sc = in[(size_t)gid * NC + 5];
    bool valid = (sc >= 0.5f);
    u32 key = 0;
    if (valid) {
        key = __float_as_uint(sc) ^ 0x80000000u;       /* positive floats: monotone */
        u32 bin = key >> 16;
        if (bin < HBASE) bin = HBASE;                  /* can't occur; safety */
        if (bin > HBASE + HBINS - 1) bin = HBASE + HBINS - 1; /* exactness-safe */
        atomicAdd(&hist[(b << 10) + (bin - HBASE)], 1u);
    }
    u64 mask = __ballot(valid);
    if (lane == 0) wcnt[wv] = __popcll(mask);
    __syncthreads();
    if (threadIdx.x == 0) {
        int c0 = wcnt[0], c1 = wcnt[1], c2 = wcnt[2], c3 = wcnt[3];
        woff[0] = 0; woff[1] = c0; woff[2] = c0 + c1; woff[3] = c0 + c1 + c2;
        blockbase = atomicAdd(&vcnt[b], c0 + c1 + c2 + c3);
    }
    __syncthreads();
    if (valid) {
        int prefix = __popcll(mask & ((1ull << lane) - 1ull));
        int p = blockbase + woff[wv] + prefix;
        u32 n = (u32)(gid - b * NANCH);
        if (p < VALIDCAP) vbuf[((size_t)b << 16) + p] = ((u64)key << 32) | (u32)(~n);
    }
}

/* 2: per-image cut bin over 1024 bins: smallest abs bin w/ suffix >= TOPK */
__global__ __launch_bounds__(256) void k2_cut(const u32* __restrict__ hist,
                                              int* __restrict__ cut) {
    __shared__ u32 psum[256];
    int b = blockIdx.x, t = threadIdx.x;
    const u32* h = hist + (b << 10);
    int base = HBINS - 4 * (t + 1);                   /* descending 4-bin chunks */
    psum[t] = h[base] + h[base + 1] + h[base + 2] + h[base + 3];
    __syncthreads();
    if (t == 0) {
        u32 cumv = 0; int res = 0; bool found = false;
        for (int c = 0; c < 256 && !found; ++c) {
            u32 cs = psum[c];
            if (cumv + cs >= (u32)TOPK) {
                int top = HBINS - 4 * c - 1;
                for (int i = top; i > top - 4; --i) {
                    cumv += h[i];
                    if (cumv >= (u32)TOPK) { res = i; found = true; break; }
                }
            } else cumv += cs;
        }
        cut[b] = found ? (res + (int)HBASE) : 0;
    }
}

/* 3: gather candidates with bin >= cut — block-aggregated atomic */
__global__ __launch_bounds__(256) void k3_gather(const u64* __restrict__ vbuf,
                          const int* __restrict__ vcnt,
                          const int* __restrict__ cut, int* __restrict__ ccnt,
                          u64* __restrict__ cbuf) {
    __shared__ int wcnt[4];
    __shared__ int woff[4];
    __shared__ int blockbase;
    int gid = blockIdx.x * 256 + threadIdx.x;
    int b = gid >> 16, i = gid & 0xffff;
    int lane = threadIdx.x & 63;
    int wv = threadIdx.x >> 6;
    int cnt = vcnt[b]; if (cnt > VALIDCAP) cnt = VALIDCAP;
    bool take = false; u64 comp = 0;
    if (i < cnt) {
        comp = vbuf[((size_t)b << 16) + i];
        take = ((u32)(comp >> 48) >= (u32)cut[b]);
    }
    u64 mask = __ballot(take);
    if (lane == 0) wcnt[wv] = __popcll(mask);
    __syncthreads();
    if (threadIdx.x == 0) {
        int c0 = wcnt[0], c1 = wcnt[1], c2 = wcnt[2], c3 = wcnt[3];
        woff[0] = 0; woff[1] = c0; woff[2] = c0 + c1; woff[3] = c0 + c1 + c2;
        blockbase = (c0 + c1 + c2 + c3) ? atomicAdd(&ccnt[b], c0 + c1 + c2 + c3) : 0;
    }
    __syncthreads();
    if (take) {
        int p = blockbase + woff[wv] + __popcll(mask & ((1ull << lane) - 1ull));
        if (p < CANDCAP) cbuf[b * CANDCAP + p] = comp;
    }
}

/* 4: per-image bitonic sort (descending) of 2048 candidates in LDS,
   one compare per thread per phase (66 phases) */
__global__ __launch_bounds__(1024) void k4_sort(u64* __restrict__ cbuf,
                                                const int* __restrict__ ccnt,
                                                int* __restrict__ Mb) {
    __shared__ u64 buf[CANDCAP];
    int b = blockIdx.x, t = threadIdx.x;
    int cnt = ccnt[b]; if (cnt > CANDCAP) cnt = CANDCAP;
    buf[t]        = (t        < cnt) ? cbuf[b * CANDCAP + t]        : 0ull;
    buf[t + 1024] = (t + 1024 < cnt) ? cbuf[b * CANDCAP + t + 1024] : 0ull;
    __syncthreads();
    for (int k = 2; k <= CANDCAP; k <<= 1)
        for (int j = k >> 1; j > 0; j >>= 1) {
            int i = ((t & ~(j - 1)) << 1) | (t & (j - 1));
            int l = i | j;
            u64 a = buf[i], c = buf[l];
            bool up = ((i & k) == 0);                    /* descending network */
            if (up ? (a < c) : (a > c)) { buf[i] = c; buf[l] = a; }
            __syncthreads();
        }
    if (t < KCAP) cbuf[b * CANDCAP + t] = buf[t];
    if (t == 0) Mb[b] = cnt < TOPK ? cnt : TOPK;
}

/* 5: decode boxes, corners, area, score, argmax label for sorted top-M */
__global__ void k5_decode(const float* __restrict__ in, const u64* __restrict__ cbuf,
                          const int* __restrict__ Mb, float* __restrict__ det,
                          float4* __restrict__ cor, float* __restrict__ area) {
    int gid = blockIdx.x * blockDim.x + threadIdx.x;
    int b = gid >> 10, k = gid & 1023;
    if (b >= NB) return;
    if (k >= Mb[b]) return;
    u64 comp = cbuf[b * CANDCAP + k];
    u32 idx = ~(u32)comp;
    int a = idx % 9; int cell = idx / 9;
    int gj = cell & 127, gi = cell >> 7;
    float ci = (gi + 0.5f) * (1.0f / GH);
    float cj = (gj + 0.5f) * (1.0f / GW);
    const float SCL[3] = {0.5f, 1.0f, 2.0f};
    float s = SCL[a / 3], r = SCL[a % 3];
    float sq = sqrtf(r);
    float ah = (s * sq) * (4.0f / GH);
    float aw = (s / sq) * (4.0f / GW);
    const float* row = in + ((size_t)b * NANCH + idx) * NC;
    float t0 = row[0], t1 = row[1], t2 = row[2], t3 = row[3], scv = row[5];
    float di = ci + t0 * ah;
    float dj = cj + t1 * aw;
    float dh = ah * expf(t2);
    float dw = aw * expf(t3);
    float i0 = di - dh * 0.5f, j0 = dj - dw * 0.5f;
    float i1 = di + dh * 0.5f, j1 = dj + dw * 0.5f;
    float best = row[6]; int lab = 0;
    for (int c = 1; c < 80; ++c) { float v = row[6 + c]; if (v > best) { best = v; lab = c; } }
    float* d = det + (size_t)(b * KCAP + k) * 8;
    d[0] = di; d[1] = dj; d[2] = dh; d[3] = dw; d[4] = (float)lab; d[5] = scv;
    cor[b * KCAP + k] = make_float4(i0, j0, i1, j1);
    area[b * KCAP + k] = (i1 - i0) * (j1 - j0);
}

/* 6: IoU suppression bitmask; 4 rows per block, cor/area staged in LDS */
__global__ __launch_bounds__(256) void k6_mask(const float4* __restrict__ cor,
                        const float* __restrict__ area,
                        const int* __restrict__ Mb, u64* __restrict__ mask) {
    __shared__ float4 scor[KCAP];
    __shared__ float sarea[KCAP];
    int b = blockIdx.x >> 8;                 /* 256 blocks per image */
    int i = ((blockIdx.x & 255) << 2) + (threadIdx.x >> 6);
    int lane = threadIdx.x & 63;
    int m = Mb[b];
    for (int idx = threadIdx.x; idx < KCAP; idx += 256) {
        scor[idx] = cor[b * KCAP + idx];
        sarea[idx] = area[b * KCAP + idx];
    }
    __syncthreads();
    if (i >= m) return;
    float4 bi = scor[i]; float ai = sarea[i];
    u64* rowp = mask + ((size_t)(b * KCAP + i)) * 16;
    for (int w = 0; w < 16; ++w) {
        int j = w * 64 + lane;
        bool pred = false;
        if (j > i && j < m) {
            float4 bj = scor[j]; float aj = sarea[j];
            float ti = fmaxf(bi.x, bj.x), tj = fmaxf(bi.y, bj.y);
            float b2 = fminf(bi.z, bj.z), b3 = fminf(bi.w, bj.w);
            float inter = fmaxf(b2 - ti, 0.0f) * fmaxf(b3 - tj, 0.0f);
            float uni = (ai + aj) - inter;
            float iou = inter / fmaxf(uni, 1e-12f);
            pred = iou > 0.75f;
        }
        u64 word = __ballot(pred);
        if (lane == w) rowp[w] = word;
    }
}

/* 7+8 merged: serial greedy scan (wave 0, register/readlane recurrence)
   then rank kept bits + emit 100 rows (both waves) */
__global__ __launch_bounds__(128) void k78_scan_out(const u64* __restrict__ mask,
                        const int* __restrict__ Mb, const float* __restrict__ det,
                        float* __restrict__ out) {
    __shared__ u64 kw[16];
    __shared__ int cum[17];
    int b = blockIdx.x, t = threadIdx.x;
    int m = Mb[b];
    if (t < 64) {
        int lane = t;
        const u64* mk = mask + (size_t)b * KCAP * 16;
        int myw = lane & 15;
        int myq = lane >> 4;
        u64 supp = 0;
        u64 colW = (lane < m) ? mk[(size_t)lane * 16 + 0] : 0ull;
        for (int g = 0; g < 16; ++g) {
            u64 rowW = colW;
            if (g + 1 < 16) {
                int rn = (g + 1) * 64 + lane;
                colW = (rn < m) ? mk[(size_t)rn * 16 + (g + 1)] : 0ull;
            }
            u64 cur = shfl64(supp, g);
            int lim = m - g * 64;
            u64 keptW = 0;
            #pragma unroll
            for (int s = 0; s < 64; ++s) {
                u64 w = readlane64(rowW, s);
                bool kept = (s < lim) && !((cur >> s) & 1ull);
                if (kept) { keptW |= (1ull << s); cur |= w; }
            }
            if (lane == 0) kw[g] = keptW;
            u64 acc = 0;
            #pragma unroll
            for (int s = 0; s < 16; ++s) {
                int r = myq * 16 + s;
                if ((keptW >> r) & 1ull)
                    acc |= mk[(size_t)(g * 64 + r) * 16 + myw];
            }
            acc |= shfl64_xor(acc, 16);
            acc |= shfl64_xor(acc, 32);
            if (lane < 16) supp |= acc;
        }
    }
    __syncthreads();
    if (t == 0) {
        int c = 0;
        for (int w = 0; w < 16; ++w) { cum[w] = c; c += __builtin_popcountll(kw[w]); }
        cum[16] = c;
    }
    __syncthreads();
    int total = cum[16];
    if (t < 100) {
        float o0 = 0, o1 = 0, o2 = 0, o3 = 0, o4 = 0, o5 = 0;
        if (t < total) {
            int w = 0;
            while (w < 15 && cum[w + 1] <= t) w++;
            int j = t - cum[w];
            u64 word = kw[w];
            for (int q = 0; q < j; ++q) word &= word - 1;
            int pos = __builtin_ctzll(word);
            int c = w * 64 + pos;
            const float* d = det + (size_t)(b * KCAP + c) * 8;
            o0 = d[0]; o1 = d[1]; o2 = d[2]; o3 = d[3]; o4 = d[4]; o5 = d[5];
        }
        float* op = out + (size_t)b * 600 + (size_t)t * 6;
        op[0] = o0; op[1] = o1; op[2] = o2; op[3] = o3; op[4] = o4; op[5] = o5;
    }
}

extern "C" void kernel_launch(void* const* d_in, const int* in_sizes, int n_in,
                              void* d_out, int out_size, void* d_ws, size_t ws_size,
                              hipStream_t stream) {
    const float* in = (const float*)d_in[0];
    float* out = (float*)d_out;
    char* ws = (char*)d_ws;
    u32* hist  = (u32*)(ws + OFF_HIST);
    int* vcnt  = (int*)(ws + OFF_VCNT);
    int* ccnt  = (int*)(ws + OFF_CCNT);
    int* cut   = (int*)(ws + OFF_CUT);
    int* Mb    = (int*)(ws + OFF_M);
    u64* vbuf  = (u64*)(ws + OFF_VBUF);
    u64* cbuf  = (u64*)(ws + OFF_CBUF);
    float* det = (float*)(ws + OFF_DET);
    float4* cor = (float4*)(ws + OFF_COR);
    float* area = (float*)(ws + OFF_AREA);
    u64* mask  = (u64*)(ws + OFF_MASK);

    hipMemsetAsync(ws, 0, MEMSET_BYTES, stream);
    k1_hist  <<<(NB * NANCH) / 256, 256, 0, stream>>>(in, hist, vcnt, vbuf);
    k2_cut   <<<NB, 256, 0, stream>>>(hist, cut);
    k3_gather<<<(NB * VALIDCAP) / 256, 256, 0, stream>>>(vbuf, vcnt, cut, ccnt, cbuf);
    k4_sort  <<<NB, 1024, 0, stream>>>(cbuf, ccnt, Mb);
    k5_decode<<<(NB * KCAP) / 256, 256, 0, stream>>>(in, cbuf, Mb, det, cor, area);
    k6_mask  <<<NB * 256, 256, 0, stream>>>(cor, area, Mb, mask);
    k78_scan_out<<<NB, 128, 0, stream>>>(mask, Mb, det, out);
}